// Round 9
// baseline (3951.605 us; speedup 1.0000x reference)
//
#include <hip/hip_runtime.h>
#include <math.h>

// Problem constants
#define BB   32
#define NN   197
#define CC   768
#define HH   12
#define DD   64
#define KWW  197
#define HIDD 3072
#define NL   12
#define RR   (BB*NN)      // 6304 rows
#define BHH  (BB*HH)      // 384 batch*head
#define NP   224          // n/kw padded to multiple of 32 (for MFMA K dim)

typedef __attribute__((ext_vector_type(8))) short short8;
typedef __attribute__((ext_vector_type(4))) float floatx4;
typedef __attribute__((ext_vector_type(4))) unsigned short us4;

__device__ __forceinline__ unsigned short f2bf(float f) {
    unsigned int u = __float_as_uint(f);
    u += 0x7fff + ((u >> 16) & 1);          // round-to-nearest-even
    return (unsigned short)(u >> 16);
}

// ---------------------------------------------------------------------------
// LayerNorm over C=768 -> bf16 output. One block (256 thr) per row.
__global__ void ln768_kernel(const float* __restrict__ in, const float* __restrict__ g,
                             const float* __restrict__ be, unsigned short* __restrict__ out) {
    int row = blockIdx.x;
    const float* x = in + (size_t)row * CC;
    unsigned short* o = out + (size_t)row * CC;
    int t = threadIdx.x;
    float v0 = x[t], v1 = x[t+256], v2 = x[t+512];
    float s = v0+v1+v2;
    float q = v0*v0+v1*v1+v2*v2;
    for (int off = 1; off < 64; off <<= 1) {
        s += __shfl_xor(s, off, 64);
        q += __shfl_xor(q, off, 64);
    }
    __shared__ float sh[8];
    int wv = t >> 6, ln = t & 63;
    if (ln == 0) { sh[wv] = s; sh[4+wv] = q; }
    __syncthreads();
    s = sh[0]+sh[1]+sh[2]+sh[3];
    q = sh[4]+sh[5]+sh[6]+sh[7];
    float mu  = s * (1.0f/CC);
    float var = q * (1.0f/CC) - mu*mu;
    float rs  = rsqrtf(var + 1e-5f);
    o[t]     = f2bf((v0-mu)*rs*g[t]     + be[t]);
    o[t+256] = f2bf((v1-mu)*rs*g[t+256] + be[t+256]);
    o[t+512] = f2bf((v2-mu)*rs*g[t+512] + be[t+512]);
}

// ---------------------------------------------------------------------------
// Fused: x2 += part0 + part1 + b2; optionally LN(x2_new) -> lnb (next layer f-LN).
__global__ void reduce_ln(float* __restrict__ x2, const float* __restrict__ part,
                          const float* __restrict__ b2,
                          const float* __restrict__ g, const float* __restrict__ be,
                          unsigned short* __restrict__ out, int do_ln) {
    int row = blockIdx.x;
    float* xp = x2 + (size_t)row * CC;
    const float* p0 = part + (size_t)row * CC;
    const float* p1 = part + (size_t)RR*CC + (size_t)row * CC;
    int t = threadIdx.x;
    float v0 = xp[t]     + p0[t]     + p1[t]     + b2[t];
    float v1 = xp[t+256] + p0[t+256] + p1[t+256] + b2[t+256];
    float v2 = xp[t+512] + p0[t+512] + p1[t+512] + b2[t+512];
    xp[t] = v0; xp[t+256] = v1; xp[t+512] = v2;
    if (!do_ln) return;
    float s = v0+v1+v2;
    float q = v0*v0+v1*v1+v2*v2;
    for (int off = 1; off < 64; off <<= 1) {
        s += __shfl_xor(s, off, 64);
        q += __shfl_xor(q, off, 64);
    }
    __shared__ float sh[8];
    int wv = t >> 6, ln = t & 63;
    if (ln == 0) { sh[wv] = s; sh[4+wv] = q; }
    __syncthreads();
    s = sh[0]+sh[1]+sh[2]+sh[3];
    q = sh[4]+sh[5]+sh[6]+sh[7];
    float mu  = s * (1.0f/CC);
    float var = q * (1.0f/CC) - mu*mu;
    float rs  = rsqrtf(var + 1e-5f);
    unsigned short* o = out + (size_t)row * CC;
    o[t]     = f2bf((v0-mu)*rs*g[t]     + be[t]);
    o[t+256] = f2bf((v1-mu)*rs*g[t+256] + be[t+256]);
    o[t+512] = f2bf((v2-mu)*rs*g[t+512] + be[t+512]);
}

// ---------------------------------------------------------------------------
// Transpose + cast fp32 [K][Nd] -> bf16 [Nd][Kpad], zero-filling k in [K,Kpad).
__global__ void transpose_cast(const float* __restrict__ in, unsigned short* __restrict__ out,
                               int K, int Nd, int Kpad) {
    __shared__ float tile[32][33];
    int n0 = blockIdx.x*32, k0 = blockIdx.y*32;
    int tx = threadIdx.x & 31, ty = threadIdx.x >> 5;   // 32 x 8
    #pragma unroll
    for (int i = 0; i < 4; i++) {
        int k = k0 + ty + i*8;
        tile[ty + i*8][tx] = (k < K && n0+tx < Nd) ? in[(size_t)k*Nd + n0 + tx] : 0.f;
    }
    __syncthreads();
    #pragma unroll
    for (int i = 0; i < 4; i++) {
        int n = n0 + ty + i*8;
        if (n < Nd && k0 + tx < Kpad) out[(size_t)n*Kpad + k0 + tx] = f2bf(tile[tx][ty + i*8]);
    }
}

// ---------------------------------------------------------------------------
// bf16 MFMA GEMM: C = A(bf16,[M][K]) @ Bt(bf16,[Nd][K])^T.
// Tile BM x BN, BK=32. KS = split-K chunks (blockIdx.z).
// EPI: 2 = +bias fast-GELU store bf16;
//      4 = QKV scatter bf16 into q[bh][n][d], k[bh][n][d], vT[bh][d][NP];
//      5 = store fp32 partial (no bias) at Cf + z*M*Nd
template<int BM, int BN, int WM, int WN, int WGN, int EPI, int KS>
__global__ __launch_bounds__(256) void gemm_bf16(
    const unsigned short* __restrict__ A, const unsigned short* __restrict__ Bt,
    const float* __restrict__ bias, float* __restrict__ Cf, unsigned short* __restrict__ Cb,
    int M, int Nd, int K)
{
    __shared__ unsigned short As[BM*32];
    __shared__ unsigned short Bs[BN*32];
    int tid  = threadIdx.x;
    int wv   = tid >> 6, lane = tid & 63;
    int wm   = wv / WGN, wn = wv % WGN;
    int bm   = blockIdx.y * BM, bn = blockIdx.x * BN;
    int quad = lane >> 4, mrow = lane & 15;
    int srow = lane >> 2;            // staging: 4 lanes per 32-elem row
    int skof = (lane & 3) * 8;       // 8 bf16 = 16B per lane
    floatx4 acc[WM][WN];
    #pragma unroll
    for (int i = 0; i < WM; i++)
        #pragma unroll
        for (int j = 0; j < WN; j++) acc[i][j] = (floatx4){0.f,0.f,0.f,0.f};

    const int Kc = K / KS;
    const int kbase = (KS > 1) ? blockIdx.z * Kc : 0;
    for (int k0 = kbase; k0 < kbase + Kc; k0 += 32) {
        #pragma unroll
        for (int i = 0; i < BM/64; i++) {
            int r  = wv*(BM/4) + i*16 + srow;
            int gr = bm + r; if (gr > M-1) gr = M-1;
            __builtin_amdgcn_global_load_lds(
                (const __attribute__((address_space(1))) void*)(A + (size_t)gr*K + k0 + skof),
                (__attribute__((address_space(3))) void*)(As + (wv*(BM/4) + i*16)*32),
                16, 0, 0);
        }
        #pragma unroll
        for (int i = 0; i < BN/64; i++) {
            int r  = wv*(BN/4) + i*16 + srow;
            int gr = bn + r; if (gr > Nd-1) gr = Nd-1;
            __builtin_amdgcn_global_load_lds(
                (const __attribute__((address_space(1))) void*)(Bt + (size_t)gr*K + k0 + skof),
                (__attribute__((address_space(3))) void*)(Bs + (wv*(BN/4) + i*16)*32),
                16, 0, 0);
        }
        __syncthreads();
        short8 af[WM], bf[WN];
        #pragma unroll
        for (int mi = 0; mi < WM; mi++)
            af[mi] = *(const short8*)&As[(wm*WM*16 + mi*16 + mrow)*32 + quad*8];
        #pragma unroll
        for (int ni = 0; ni < WN; ni++)
            bf[ni] = *(const short8*)&Bs[(wn*WN*16 + ni*16 + mrow)*32 + quad*8];
        #pragma unroll
        for (int mi = 0; mi < WM; mi++)
            #pragma unroll
            for (int ni = 0; ni < WN; ni++)
                acc[mi][ni] = __builtin_amdgcn_mfma_f32_16x16x32_bf16(af[mi], bf[ni], acc[mi][ni], 0, 0, 0);
        __syncthreads();
    }

    float* Cfz = (EPI == 5) ? (Cf + (size_t)blockIdx.z * M * Nd) : Cf;
    #pragma unroll
    for (int mi = 0; mi < WM; mi++) {
        int row0 = bm + wm*WM*16 + mi*16 + quad*4;
        #pragma unroll
        for (int ni = 0; ni < WN; ni++) {
            int col = bn + wn*WN*16 + ni*16 + mrow;
            float bv = (EPI == 2) ? bias[col] : 0.f;
            #pragma unroll
            for (int r = 0; r < 4; r++) {
                int row = row0 + r;
                if (row >= M) continue;
                float v = acc[mi][ni][r] + bv;
                if (EPI == 2) {
                    // tanh-form GELU via hw exp (err ~3e-4, < bf16 grain)
                    v = v / (1.0f + __expf(-1.5957691216f*v*(1.0f + 0.044715f*v*v)));
                    Cb[(size_t)row*Nd + col] = f2bf(v);
                } else if (EPI == 5) {
                    Cfz[(size_t)row*Nd + col] = v;
                } else if (EPI == 4) {
                    int sel = col / CC;
                    int rem = col - sel*CC;
                    int h = rem >> 6, d = rem & 63;
                    int b = row / NN, n = row - b*NN;
                    int bh = b*HH + h;
                    unsigned short val = f2bf(v);
                    if (sel < 2)
                        Cb[((size_t)sel*BHH + bh)*NN*DD + (size_t)n*DD + d] = val;
                    else
                        Cb[(size_t)2*BHH*NN*DD + (size_t)bh*DD*NP + (size_t)d*NP + n] = val;
                } else {
                    Cf[(size_t)row*Nd + col] = v;
                }
            }
        }
    }
}

// ---------------------------------------------------------------------------
// Fused qk + fc + LN + softmax -> PT  (v2: no K/fw LDS staging, 1 barrier).
// Grid (4, BHH); block = 4 waves; row tile bm = blockIdx.x*64.
// Phase 1: S1[64][224] = 0.125 * Q @ K^T, K B-frags direct from global
//   (rows clamped to 196 -> dup cols; killed by fc_wt k-pad zeros in phase 2).
// Phase 2: S2 = S1 @ fc_w (fw B-frags direct from global, rows clamped),
//   +bias, rowwise LN + softmax, store PT transposed. S1 LDS is same-wave
//   write->read so no barrier; the single barrier covers gls/bls/bbs.
__global__ __launch_bounds__(256) void attn_score(
    const unsigned short* __restrict__ qb,   // [bh][NN][DD]
    const unsigned short* __restrict__ kb,   // [bh][NN][DD]
    const unsigned short* __restrict__ fw,   // fc_wt [KWW][NP] (k-pad zero)
    const float* __restrict__ fbias,         // fc_b
    const float* __restrict__ g, const float* __restrict__ be,  // attn LN
    unsigned short* __restrict__ PT)         // [bh][NP][NP]
{
    int bh = blockIdx.y;
    int bm = blockIdx.x * 64;
    __shared__ unsigned short S1s[64*NP];    // 28 KB
    __shared__ float gls[NP], bls[NP], bbs[NP];
    int tid = threadIdx.x;
    if (tid < NP) {
        bool vc = tid < KWW;
        gls[tid] = vc ? g[tid]     : 1.f;
        bls[tid] = vc ? be[tid]    : 0.f;
        bbs[tid] = vc ? fbias[tid] : 0.f;
    }
    int wv = tid >> 6, lane = tid & 63;
    int quad = lane >> 4, mrow = lane & 15;
    const unsigned short* Kb = kb + (size_t)bh*NN*DD;

    // Q A-fragments straight from global (own rows only)
    int qrow = bm + wv*16 + mrow; if (qrow > NN-1) qrow = NN-1;
    short8 aq0 = *(const short8*)&qb[((size_t)bh*NN + qrow)*DD + quad*8];
    short8 aq1 = *(const short8*)&qb[((size_t)bh*NN + qrow)*DD + 32 + quad*8];

    // phase 1: 14 independent col-tiles
    #pragma unroll
    for (int ni = 0; ni < 14; ni++) {
        int kr = ni*16 + mrow; if (kr > NN-1) kr = NN-1;
        short8 bf0 = *(const short8*)&Kb[(size_t)kr*DD + quad*8];
        short8 bf1 = *(const short8*)&Kb[(size_t)kr*DD + 32 + quad*8];
        floatx4 a = (floatx4){0.f,0.f,0.f,0.f};
        a = __builtin_amdgcn_mfma_f32_16x16x32_bf16(aq0, bf0, a, 0, 0, 0);
        a = __builtin_amdgcn_mfma_f32_16x16x32_bf16(aq1, bf1, a, 0, 0, 0);
        #pragma unroll
        for (int r = 0; r < 4; r++)
            S1s[(size_t)(wv*16 + quad*4 + r)*NP + ni*16 + mrow] = f2bf(a[r]*0.125f);
    }
    __syncthreads();   // gls/bls/bbs visibility (S1s is same-wave)

    // phase 2: S2 = S1 @ fc_w  (14 independent acc chains)
    floatx4 acc[14];
    #pragma unroll
    for (int j = 0; j < 14; j++) acc[j] = (floatx4){0.f,0.f,0.f,0.f};
    #pragma unroll
    for (int k0 = 0; k0 < 7; k0++) {
        short8 af = *(const short8*)&S1s[(size_t)(wv*16 + mrow)*NP + k0*32 + quad*8];
        #pragma unroll
        for (int ni = 0; ni < 14; ni++) {
            int fr = ni*16 + mrow; if (fr > KWW-1) fr = KWW-1;
            short8 bf = *(const short8*)&fw[(size_t)fr*NP + k0*32 + quad*8];
            acc[ni] = __builtin_amdgcn_mfma_f32_16x16x32_bf16(af, bf, acc[ni], 0, 0, 0);
        }
    }

    // epilogue: +bias, row LN, softmax, transposed store
    float s[4] = {}, q[4] = {};
    #pragma unroll
    for (int ni = 0; ni < 14; ni++) {
        int col = ni*16 + mrow;
        float cm = (col < KWW) ? 1.f : 0.f;
        #pragma unroll
        for (int r = 0; r < 4; r++) {
            float x = acc[ni][r] + bbs[col];
            acc[ni][r] = x;
            s[r] += x*cm; q[r] += x*x*cm;
        }
    }
    #pragma unroll
    for (int o = 1; o < 16; o <<= 1)
        #pragma unroll
        for (int r = 0; r < 4; r++) {
            s[r] += __shfl_xor(s[r], o, 64);
            q[r] += __shfl_xor(q[r], o, 64);
        }
    float mu[4], rs[4], mx[4];
    #pragma unroll
    for (int r = 0; r < 4; r++) {
        mu[r] = s[r] * (1.0f/KWW);
        float var = q[r] * (1.0f/KWW) - mu[r]*mu[r];
        rs[r] = rsqrtf(var + 1e-5f);
        mx[r] = -1e30f;
    }
    #pragma unroll
    for (int ni = 0; ni < 14; ni++) {
        int col = ni*16 + mrow;
        bool vc = col < KWW;
        #pragma unroll
        for (int r = 0; r < 4; r++) {
            float x = (acc[ni][r] - mu[r]) * rs[r] * gls[col] + bls[col];
            acc[ni][r] = x;
            if (vc) mx[r] = fmaxf(mx[r], x);
        }
    }
    #pragma unroll
    for (int o = 1; o < 16; o <<= 1)
        #pragma unroll
        for (int r = 0; r < 4; r++)
            mx[r] = fmaxf(mx[r], __shfl_xor(mx[r], o, 64));
    float se[4] = {};
    #pragma unroll
    for (int ni = 0; ni < 14; ni++) {
        int col = ni*16 + mrow;
        float cm = (col < KWW) ? 1.f : 0.f;
        #pragma unroll
        for (int r = 0; r < 4; r++) {
            float p = __expf(acc[ni][r] - mx[r]) * cm;
            acc[ni][r] = p;
            se[r] += p;
        }
    }
    #pragma unroll
    for (int o = 1; o < 16; o <<= 1)
        #pragma unroll
        for (int r = 0; r < 4; r++)
            se[r] += __shfl_xor(se[r], o, 64);
    unsigned short* Pb = PT + (size_t)bh*NP*NP;
    int row0 = bm + wv*16 + quad*4;
    float inv0 = 1.0f/se[0], inv1 = 1.0f/se[1], inv2 = 1.0f/se[2], inv3 = 1.0f/se[3];
    #pragma unroll
    for (int ni = 0; ni < 14; ni++) {
        int col = ni*16 + mrow;
        if (col >= KWW) continue;
        if (row0 + 3 < NN) {
            us4 o = { f2bf(acc[ni][0]*inv0), f2bf(acc[ni][1]*inv1),
                      f2bf(acc[ni][2]*inv2), f2bf(acc[ni][3]*inv3) };
            *(us4*)&Pb[(size_t)col*NP + row0] = o;
        } else {
            float invs[4] = {inv0, inv1, inv2, inv3};
            #pragma unroll
            for (int r = 0; r < 4; r++)
                if (row0 + r < NN)
                    Pb[(size_t)col*NP + row0 + r] = f2bf(acc[ni][r]*invs[r]);
        }
    }
}

// ---------------------------------------------------------------------------
// Fused yv + fc2, split by d: grid (4, BHH). v2: paired iterations for ILP.
__global__ __launch_bounds__(256) void attn_out2(
    const unsigned short* __restrict__ PT,   // [bh][NP][NP]
    const unsigned short* __restrict__ vT,   // [bh][DD][NP] (n-pad zeroed)
    const unsigned short* __restrict__ fw,   // fc2_wt [NP][NP] (pad rows/cols zero)
    const float* __restrict__ bias,          // fc2_b [197]
    float* __restrict__ x1)
{
    int dt = blockIdx.x;                 // d-tile 0..3
    int bh = blockIdx.y; int b = bh / HH, h = bh - b*HH;
    __shared__ unsigned short yT[16*232];
    int wv = threadIdx.x >> 6, lane = threadIdx.x & 63;
    int quad = lane >> 4, mrow = lane & 15;
    const unsigned short* Pb = PT + (size_t)bh*NP*NP;
    const unsigned short* Vb = vT + (size_t)bh*DD*NP + (size_t)(dt*16)*NP;

    short8 bfv[7];
    #pragma unroll
    for (int kc = 0; kc < 7; kc++)
        bfv[kc] = *(const short8*)&Vb[(size_t)mrow*NP + kc*32 + quad*8];
    // Stage A: 14 kw-tiles over 4 waves, paired for ILP (t0 in {wv, wv+8}, t1=t0+4)
    #pragma unroll
    for (int i = 0; i < 2; i++) {
        int t0 = wv + i*8, t1 = t0 + 4;
        bool v1 = t1 < 14;
        floatx4 a0 = (floatx4){0.f,0.f,0.f,0.f};
        floatx4 a1 = (floatx4){0.f,0.f,0.f,0.f};
        #pragma unroll
        for (int kc = 0; kc < 7; kc++) {
            short8 p0 = *(const short8*)&Pb[(size_t)(t0*16 + mrow)*NP + kc*32 + quad*8];
            a0 = __builtin_amdgcn_mfma_f32_16x16x32_bf16(p0, bfv[kc], a0, 0, 0, 0);
            if (v1) {
                short8 p1 = *(const short8*)&Pb[(size_t)(t1*16 + mrow)*NP + kc*32 + quad*8];
                a1 = __builtin_amdgcn_mfma_f32_16x16x32_bf16(p1, bfv[kc], a1, 0, 0, 0);
            }
        }
        us4 o0 = { f2bf(a0[0]), f2bf(a0[1]), f2bf(a0[2]), f2bf(a0[3]) };
        *(us4*)&yT[mrow*232 + t0*16 + quad*4] = o0;
        if (v1) {
            us4 o1 = { f2bf(a1[0]), f2bf(a1[1]), f2bf(a1[2]), f2bf(a1[3]) };
            *(us4*)&yT[mrow*232 + t1*16 + quad*4] = o1;
        }
    }
    __syncthreads();

    short8 yf[7];
    #pragma unroll
    for (int kc = 0; kc < 7; kc++)
        yf[kc] = *(const short8*)&yT[mrow*232 + kc*32 + quad*8];
    float* xb = x1 + (size_t)b*NN*CC + (size_t)h*DD + dt*16 + mrow;
    // Stage B: 13 n-tiles over 4 waves, paired for ILP
    #pragma unroll
    for (int i = 0; i < 2; i++) {
        int n0t = wv + i*8, n1t = n0t + 4;
        bool v1 = n1t < 13;
        floatx4 a0 = (floatx4){0.f,0.f,0.f,0.f};
        floatx4 a1 = (floatx4){0.f,0.f,0.f,0.f};
        #pragma unroll
        for (int kc = 0; kc < 7; kc++) {
            short8 f0 = *(const short8*)&fw[(size_t)(n0t*16 + mrow)*NP + kc*32 + quad*8];
            a0 = __builtin_amdgcn_mfma_f32_16x16x32_bf16(f0, yf[kc], a0, 0, 0, 0);
            if (v1) {
                short8 f1 = *(const short8*)&fw[(size_t)(n1t*16 + mrow)*NP + kc*32 + quad*8];
                a1 = __builtin_amdgcn_mfma_f32_16x16x32_bf16(f1, yf[kc], a1, 0, 0, 0);
            }
        }
        #pragma unroll
        for (int r = 0; r < 4; r++) {
            int n = n0t*16 + quad*4 + r;
            if (n < NN) xb[(size_t)n*CC] += a0[r] + bias[n];
        }
        if (v1) {
            #pragma unroll
            for (int r = 0; r < 4; r++) {
                int n = n1t*16 + quad*4 + r;
                if (n < NN) xb[(size_t)n*CC] += a1[r] + bias[n];
            }
        }
    }
}

// ---------------------------------------------------------------------------
__global__ void init_kernel(const float* __restrict__ x, float* __restrict__ x1,
                            float* __restrict__ x2, int n) {
    int i = blockIdx.x*256 + threadIdx.x;
    if (i < n) { float v = x[i]; x1[i] = v; x2[i] = v; }
}
__global__ void final_kernel(const float* __restrict__ x1, const float* __restrict__ x2,
                             float* __restrict__ o, int n) {
    int i = blockIdx.x*256 + threadIdx.x;
    if (i < n) o[i] = 0.5f*(x1[i]+x2[i]);
}

// ---------------------------------------------------------------------------
extern "C" void kernel_launch(void* const* d_in, const int* in_sizes, int n_in,
                              void* d_out, int out_size, void* d_ws, size_t ws_size,
                              hipStream_t stream) {
    const float* x     = (const float*)d_in[0];
    const float* qkv_w = (const float*)d_in[1];
    const float* fc_w  = (const float*)d_in[2];
    const float* fc_b  = (const float*)d_in[3];
    const float* alng  = (const float*)d_in[4];
    const float* alnb  = (const float*)d_in[5];
    const float* fc2w  = (const float*)d_in[6];
    const float* fc2b  = (const float*)d_in[7];
    const float* w1    = (const float*)d_in[8];
    const float* b1    = (const float*)d_in[9];
    const float* w2    = (const float*)d_in[10];
    const float* b2    = (const float*)d_in[11];
    const float* flng  = (const float*)d_in[12];
    const float* flnb  = (const float*)d_in[13];
    const float* glng  = (const float*)d_in[14];
    const float* glnb  = (const float*)d_in[15];
    float* out = (float*)d_out;

    float* ws = (float*)d_ws;
    size_t off = 0;
    float* x1 = ws + off; off += (size_t)RR*CC;
    float* x2 = ws + off; off += (size_t)RR*CC;
    float* part = ws + off; off += (size_t)2*RR*CC;     // MLP2 split-K partials
    unsigned short* lnb = (unsigned short*)(ws + off); off += (size_t)RR*CC/2;
    // qkv bf16 region: q[bh][n][64], k[bh][n][64], vT[bh][64][NP]
    unsigned short* qkvo = (unsigned short*)(ws + off);
    unsigned short* qb = qkvo;
    unsigned short* kb = qkvo + (size_t)BHH*NN*DD;
    unsigned short* vT = qkvo + (size_t)2*BHH*NN*DD;
    off += ((size_t)2*BHH*NN*DD + (size_t)BHH*DD*NP + 1) / 2;
    unsigned short* PT   = (unsigned short*)(ws + off); off += (size_t)BHH*NP*NP/2;
    unsigned short* hid  = (unsigned short*)(ws + off); off += (size_t)RR*HIDD/2;
    unsigned short* qkv_wt = (unsigned short*)(ws + off); off += (size_t)3*CC*CC/2;
    unsigned short* w1t    = (unsigned short*)(ws + off); off += (size_t)CC*HIDD/2;
    unsigned short* w2t    = (unsigned short*)(ws + off); off += (size_t)CC*HIDD/2;
    unsigned short* fc_wt  = (unsigned short*)(ws + off); off += (size_t)NN*NP/2 + 16;
    unsigned short* fc2_wt = (unsigned short*)(ws + off); off += (size_t)NP*NP/2 + 16;

    // Zero pads: vT (n-pad cols must be 0), fc2_wt (pad rows read by attn_out2).
    hipMemsetAsync(vT, 0, (size_t)BHH*DD*NP*2, stream);
    hipMemsetAsync(fc2_wt, 0, (size_t)NP*NP*2, stream);

    // Weight prep: bf16 transposed (+padded) copies, once per launch.
    transpose_cast<<<dim3(72, 24), 256, 0, stream>>>(qkv_w, qkv_wt, CC, 3*CC, CC);
    transpose_cast<<<dim3(96, 24), 256, 0, stream>>>(w1, w1t, CC, HIDD, CC);
    transpose_cast<<<dim3(24, 96), 256, 0, stream>>>(w2, w2t, HIDD, CC, HIDD);
    transpose_cast<<<dim3(7, 7),   256, 0, stream>>>(fc_w,  fc_wt,  NN, KWW, NP);
    transpose_cast<<<dim3(7, 7),   256, 0, stream>>>(fc2w,  fc2_wt, KWW, NN, NP);

    const int nel = RR*CC;
    init_kernel<<<(nel+255)/256, 256, 0, stream>>>(x, x1, x2, nel);

    const int MT = (RR + 127) / 128;   // 50 row-tiles
    // f-LN for layer 0 (subsequent f-LNs are fused into reduce_ln)
    ln768_kernel<<<RR, 256, 0, stream>>>(x2, flng, flnb, lnb);
    for (int l = 0; l < NL; l++) {
        // --- attention branch: y1 = x1 + attn(LN(x2)) ---  (lnb holds f-LN(x2))
        gemm_bf16<128,128,4,4,2,4,1><<<dim3(3*CC/128, MT), 256, 0, stream>>>(
            lnb, qkv_wt, nullptr, nullptr, qb, RR, 3*CC, CC);
        // fused qk + fc + LN + softmax -> PT (transposed bf16)
        attn_score<<<dim3(4, BHH), 256, 0, stream>>>(
            qb, kb, fc_wt, fc_b, alng, alnb, PT);
        // fused yv + fc2 -> x1 += (split by d: 4 blocks/bh)
        attn_out2<<<dim3(4, BHH), 256, 0, stream>>>(PT, vT, fc2_wt, fc2b, x1);
        // --- mlp branch: y2 = x2 + mlp(LN(y1)) ---
        ln768_kernel<<<RR, 256, 0, stream>>>(x1, glng + l*CC, glnb + l*CC, lnb);
        gemm_bf16<128,128,4,4,2,2,1><<<dim3(HIDD/128, MT), 256, 0, stream>>>(
            lnb, w1t, b1, nullptr, hid, RR, HIDD, CC);
        // MLP2: split-K=2, BN=128 (halve A re-reads): 6 x 50 x 2 = 600 blocks
        gemm_bf16<128,128,4,4,2,5,2><<<dim3(CC/128, MT, 2), 256, 0, stream>>>(
            hid, w2t, nullptr, part, nullptr, RR, CC, HIDD);
        // x2 += part0+part1+b2, fused with next layer's f-LN -> lnb
        reduce_ln<<<RR, 256, 0, stream>>>(
            x2, part, b2, flng + ((l+1 < NL) ? (l+1)*CC : 0),
            flnb + ((l+1 < NL) ? (l+1)*CC : 0), lnb, (l+1 < NL) ? 1 : 0);
    }
    final_kernel<<<(nel+255)/256, 256, 0, stream>>>(x1, x2, out, nel);
}

// Round 10
// 3715.407 us; speedup vs baseline: 1.0636x; 1.0636x over previous
//
#include <hip/hip_runtime.h>
#include <math.h>

// Problem constants
#define BB   32
#define NN   197
#define CC   768
#define HH   12
#define DD   64
#define KWW  197
#define HIDD 3072
#define NL   12
#define RR   (BB*NN)      // 6304 rows
#define BHH  (BB*HH)      // 384 batch*head
#define NP   224          // n/kw padded to multiple of 32 (for MFMA K dim)

typedef __attribute__((ext_vector_type(8))) short short8;
typedef __attribute__((ext_vector_type(4))) float floatx4;
typedef __attribute__((ext_vector_type(4))) unsigned short us4;

__device__ __forceinline__ unsigned short f2bf(float f) {
    unsigned int u = __float_as_uint(f);
    u += 0x7fff + ((u >> 16) & 1);          // round-to-nearest-even
    return (unsigned short)(u >> 16);
}

// ---------------------------------------------------------------------------
// LayerNorm over C=768 -> bf16 output. One block (256 thr) per row.
__global__ void ln768_kernel(const float* __restrict__ in, const float* __restrict__ g,
                             const float* __restrict__ be, unsigned short* __restrict__ out) {
    int row = blockIdx.x;
    const float* x = in + (size_t)row * CC;
    unsigned short* o = out + (size_t)row * CC;
    int t = threadIdx.x;
    float v0 = x[t], v1 = x[t+256], v2 = x[t+512];
    float s = v0+v1+v2;
    float q = v0*v0+v1*v1+v2*v2;
    for (int off = 1; off < 64; off <<= 1) {
        s += __shfl_xor(s, off, 64);
        q += __shfl_xor(q, off, 64);
    }
    __shared__ float sh[8];
    int wv = t >> 6, ln = t & 63;
    if (ln == 0) { sh[wv] = s; sh[4+wv] = q; }
    __syncthreads();
    s = sh[0]+sh[1]+sh[2]+sh[3];
    q = sh[4]+sh[5]+sh[6]+sh[7];
    float mu  = s * (1.0f/CC);
    float var = q * (1.0f/CC) - mu*mu;
    float rs  = rsqrtf(var + 1e-5f);
    o[t]     = f2bf((v0-mu)*rs*g[t]     + be[t]);
    o[t+256] = f2bf((v1-mu)*rs*g[t+256] + be[t+256]);
    o[t+512] = f2bf((v2-mu)*rs*g[t+512] + be[t+512]);
}

// ---------------------------------------------------------------------------
// Fused: x2 += part0 + part1 + b2; optionally LN(x2_new) -> lnb (next layer f-LN).
__global__ void reduce_ln(float* __restrict__ x2, const float* __restrict__ part,
                          const float* __restrict__ b2,
                          const float* __restrict__ g, const float* __restrict__ be,
                          unsigned short* __restrict__ out, int do_ln) {
    int row = blockIdx.x;
    float* xp = x2 + (size_t)row * CC;
    const float* p0 = part + (size_t)row * CC;
    const float* p1 = part + (size_t)RR*CC + (size_t)row * CC;
    int t = threadIdx.x;
    float v0 = xp[t]     + p0[t]     + p1[t]     + b2[t];
    float v1 = xp[t+256] + p0[t+256] + p1[t+256] + b2[t+256];
    float v2 = xp[t+512] + p0[t+512] + p1[t+512] + b2[t+512];
    xp[t] = v0; xp[t+256] = v1; xp[t+512] = v2;
    if (!do_ln) return;
    float s = v0+v1+v2;
    float q = v0*v0+v1*v1+v2*v2;
    for (int off = 1; off < 64; off <<= 1) {
        s += __shfl_xor(s, off, 64);
        q += __shfl_xor(q, off, 64);
    }
    __shared__ float sh[8];
    int wv = t >> 6, ln = t & 63;
    if (ln == 0) { sh[wv] = s; sh[4+wv] = q; }
    __syncthreads();
    s = sh[0]+sh[1]+sh[2]+sh[3];
    q = sh[4]+sh[5]+sh[6]+sh[7];
    float mu  = s * (1.0f/CC);
    float var = q * (1.0f/CC) - mu*mu;
    float rs  = rsqrtf(var + 1e-5f);
    unsigned short* o = out + (size_t)row * CC;
    o[t]     = f2bf((v0-mu)*rs*g[t]     + be[t]);
    o[t+256] = f2bf((v1-mu)*rs*g[t+256] + be[t+256]);
    o[t+512] = f2bf((v2-mu)*rs*g[t+512] + be[t+512]);
}

// ---------------------------------------------------------------------------
// Transpose + cast fp32 [K][Nd] -> bf16 [Nd][Kpad], zero-filling k in [K,Kpad).
__global__ void transpose_cast(const float* __restrict__ in, unsigned short* __restrict__ out,
                               int K, int Nd, int Kpad) {
    __shared__ float tile[32][33];
    int n0 = blockIdx.x*32, k0 = blockIdx.y*32;
    int tx = threadIdx.x & 31, ty = threadIdx.x >> 5;   // 32 x 8
    #pragma unroll
    for (int i = 0; i < 4; i++) {
        int k = k0 + ty + i*8;
        tile[ty + i*8][tx] = (k < K && n0+tx < Nd) ? in[(size_t)k*Nd + n0 + tx] : 0.f;
    }
    __syncthreads();
    #pragma unroll
    for (int i = 0; i < 4; i++) {
        int n = n0 + ty + i*8;
        if (n < Nd && k0 + tx < Kpad) out[(size_t)n*Kpad + k0 + tx] = f2bf(tile[tx][ty + i*8]);
    }
}

// ---------------------------------------------------------------------------
// bf16 MFMA GEMM: C = A(bf16,[M][K]) @ Bt(bf16,[Nd][K])^T.
// Tile BM x BN, BK=32. KS = split-K chunks (blockIdx.z).
// EPI: 2 = +bias fast-GELU store bf16;
//      4 = QKV scatter bf16 into q[bh][n][d], k[bh][n][d], vT[bh][d][NP];
//      5 = store fp32 partial (no bias) at Cf + z*M*Nd
template<int BM, int BN, int WM, int WN, int WGN, int EPI, int KS>
__global__ __launch_bounds__(256) void gemm_bf16(
    const unsigned short* __restrict__ A, const unsigned short* __restrict__ Bt,
    const float* __restrict__ bias, float* __restrict__ Cf, unsigned short* __restrict__ Cb,
    int M, int Nd, int K)
{
    __shared__ unsigned short As[BM*32];
    __shared__ unsigned short Bs[BN*32];
    int tid  = threadIdx.x;
    int wv   = tid >> 6, lane = tid & 63;
    int wm   = wv / WGN, wn = wv % WGN;
    int bm   = blockIdx.y * BM, bn = blockIdx.x * BN;
    int quad = lane >> 4, mrow = lane & 15;
    int srow = lane >> 2;            // staging: 4 lanes per 32-elem row
    int skof = (lane & 3) * 8;       // 8 bf16 = 16B per lane
    floatx4 acc[WM][WN];
    #pragma unroll
    for (int i = 0; i < WM; i++)
        #pragma unroll
        for (int j = 0; j < WN; j++) acc[i][j] = (floatx4){0.f,0.f,0.f,0.f};

    const int Kc = K / KS;
    const int kbase = (KS > 1) ? blockIdx.z * Kc : 0;
    for (int k0 = kbase; k0 < kbase + Kc; k0 += 32) {
        #pragma unroll
        for (int i = 0; i < BM/64; i++) {
            int r  = wv*(BM/4) + i*16 + srow;
            int gr = bm + r; if (gr > M-1) gr = M-1;
            __builtin_amdgcn_global_load_lds(
                (const __attribute__((address_space(1))) void*)(A + (size_t)gr*K + k0 + skof),
                (__attribute__((address_space(3))) void*)(As + (wv*(BM/4) + i*16)*32),
                16, 0, 0);
        }
        #pragma unroll
        for (int i = 0; i < BN/64; i++) {
            int r  = wv*(BN/4) + i*16 + srow;
            int gr = bn + r; if (gr > Nd-1) gr = Nd-1;
            __builtin_amdgcn_global_load_lds(
                (const __attribute__((address_space(1))) void*)(Bt + (size_t)gr*K + k0 + skof),
                (__attribute__((address_space(3))) void*)(Bs + (wv*(BN/4) + i*16)*32),
                16, 0, 0);
        }
        __syncthreads();
        short8 af[WM], bf[WN];
        #pragma unroll
        for (int mi = 0; mi < WM; mi++)
            af[mi] = *(const short8*)&As[(wm*WM*16 + mi*16 + mrow)*32 + quad*8];
        #pragma unroll
        for (int ni = 0; ni < WN; ni++)
            bf[ni] = *(const short8*)&Bs[(wn*WN*16 + ni*16 + mrow)*32 + quad*8];
        #pragma unroll
        for (int mi = 0; mi < WM; mi++)
            #pragma unroll
            for (int ni = 0; ni < WN; ni++)
                acc[mi][ni] = __builtin_amdgcn_mfma_f32_16x16x32_bf16(af[mi], bf[ni], acc[mi][ni], 0, 0, 0);
        __syncthreads();
    }

    float* Cfz = (EPI == 5) ? (Cf + (size_t)blockIdx.z * M * Nd) : Cf;
    #pragma unroll
    for (int mi = 0; mi < WM; mi++) {
        int row0 = bm + wm*WM*16 + mi*16 + quad*4;
        #pragma unroll
        for (int ni = 0; ni < WN; ni++) {
            int col = bn + wn*WN*16 + ni*16 + mrow;
            float bv = (EPI == 2) ? bias[col] : 0.f;
            #pragma unroll
            for (int r = 0; r < 4; r++) {
                int row = row0 + r;
                if (row >= M) continue;
                float v = acc[mi][ni][r] + bv;
                if (EPI == 2) {
                    // tanh-form GELU via hw exp (err ~3e-4, < bf16 grain)
                    v = v / (1.0f + __expf(-1.5957691216f*v*(1.0f + 0.044715f*v*v)));
                    Cb[(size_t)row*Nd + col] = f2bf(v);
                } else if (EPI == 5) {
                    Cfz[(size_t)row*Nd + col] = v;
                } else if (EPI == 4) {
                    int sel = col / CC;
                    int rem = col - sel*CC;
                    int h = rem >> 6, d = rem & 63;
                    int b = row / NN, n = row - b*NN;
                    int bh = b*HH + h;
                    unsigned short val = f2bf(v);
                    if (sel < 2)
                        Cb[((size_t)sel*BHH + bh)*NN*DD + (size_t)n*DD + d] = val;
                    else
                        Cb[(size_t)2*BHH*NN*DD + (size_t)bh*DD*NP + (size_t)d*NP + n] = val;
                } else {
                    Cf[(size_t)row*Nd + col] = v;
                }
            }
        }
    }
}

// ---------------------------------------------------------------------------
// Fused qk + fc + LN + softmax -> PT  (round-8 staged variant: K panel and
// fc_w chunks staged to LDS cooperatively — 4x amortization across waves).
// Grid (4, BHH); block = 4 waves; row tile bm = blockIdx.x*64 (rows of S).
__global__ __launch_bounds__(256) void attn_score(
    const unsigned short* __restrict__ qb,   // [bh][NN][DD]
    const unsigned short* __restrict__ kb,   // [bh][NN][DD]
    const unsigned short* __restrict__ fw,   // fc_wt [KWW][NP] (k-pad zero)
    const float* __restrict__ fbias,         // fc_b
    const float* __restrict__ g, const float* __restrict__ be,  // attn LN
    unsigned short* __restrict__ PT)         // [bh][NP][NP]
{
    int bh = blockIdx.y;
    int bm = blockIdx.x * 64;
    __shared__ unsigned short Ks[224*DD];    // 28 KB
    __shared__ unsigned short S1s[64*NP];    // 28 KB
    __shared__ unsigned short Bs[224*32];    // 14 KB
    __shared__ float gls[NP], bls[NP], bbs[NP];
    int tid = threadIdx.x;
    if (tid < NP) {
        bool vc = tid < KWW;
        gls[tid] = vc ? g[tid]     : 1.f;
        bls[tid] = vc ? be[tid]    : 0.f;
        bbs[tid] = vc ? fbias[tid] : 0.f;
    }
    int wv = tid >> 6, lane = tid & 63;
    int quad = lane >> 4, mrow = lane & 15;

    // stage K rows [wv*56, wv*56+56) -> Ks (16B/lane, 8 rows per issue)
    {
        int lrow = lane >> 3, lko = (lane & 7) * 8;
        #pragma unroll
        for (int i = 0; i < 7; i++) {
            int r = wv*56 + i*8 + lrow;
            __builtin_amdgcn_global_load_lds(
                (const __attribute__((address_space(1))) void*)(kb + ((size_t)bh*NN + r)*DD + lko),
                (__attribute__((address_space(3))) void*)(Ks + (size_t)(wv*56 + i*8)*DD),
                16, 0, 0);
        }
    }
    // Q A-fragments straight from global (own rows only)
    int qrow = bm + wv*16 + mrow; if (qrow > NN-1) qrow = NN-1;
    short8 aq0 = *(const short8*)&qb[((size_t)bh*NN + qrow)*DD + quad*8];
    short8 aq1 = *(const short8*)&qb[((size_t)bh*NN + qrow)*DD + 32 + quad*8];
    __syncthreads();

    // phase 1 MFMA: acc[ni] = Q(16 rows) x K(cols ni*16..)
    #pragma unroll
    for (int ni = 0; ni < 14; ni++) {
        floatx4 a = (floatx4){0.f,0.f,0.f,0.f};
        short8 bf0 = *(const short8*)&Ks[(size_t)(ni*16 + mrow)*DD + quad*8];
        short8 bf1 = *(const short8*)&Ks[(size_t)(ni*16 + mrow)*DD + 32 + quad*8];
        a = __builtin_amdgcn_mfma_f32_16x16x32_bf16(aq0, bf0, a, 0, 0, 0);
        a = __builtin_amdgcn_mfma_f32_16x16x32_bf16(aq1, bf1, a, 0, 0, 0);
        // C layout: row = wv*16 + quad*4 + r, col = ni*16 + mrow -> S1s row-major
        #pragma unroll
        for (int r = 0; r < 4; r++)
            S1s[(size_t)(wv*16 + quad*4 + r)*NP + ni*16 + mrow] = f2bf(a[r]*0.125f);
    }
    __syncthreads();

    // phase 2: S2 = S1 @ fc_w (fw staged chunk-wise into Bs)
    floatx4 acc[14];
    #pragma unroll
    for (int j = 0; j < 14; j++) acc[j] = (floatx4){0.f,0.f,0.f,0.f};
    for (int k0 = 0; k0 < 7; k0++) {
        for (int c = wv; c < 14; c += 4) {
            int gr = c*16 + (lane >> 2); if (gr > KWW-1) gr = KWW-1;
            __builtin_amdgcn_global_load_lds(
                (const __attribute__((address_space(1))) void*)(fw + (size_t)gr*NP + k0*32 + (lane & 3)*8),
                (__attribute__((address_space(3))) void*)(Bs + (size_t)(c*16)*32),
                16, 0, 0);
        }
        __syncthreads();
        short8 af = *(const short8*)&S1s[(size_t)(wv*16 + mrow)*NP + k0*32 + quad*8];
        #pragma unroll
        for (int ni = 0; ni < 14; ni++) {
            short8 bf = *(const short8*)&Bs[(size_t)(ni*16 + mrow)*32 + quad*8];
            acc[ni] = __builtin_amdgcn_mfma_f32_16x16x32_bf16(af, bf, acc[ni], 0, 0, 0);
        }
        __syncthreads();
    }

    // epilogue: +bias, row LN, softmax, transposed store
    float s[4] = {}, q[4] = {};
    #pragma unroll
    for (int ni = 0; ni < 14; ni++) {
        int col = ni*16 + mrow;
        float cm = (col < KWW) ? 1.f : 0.f;
        #pragma unroll
        for (int r = 0; r < 4; r++) {
            float x = acc[ni][r] + bbs[col];
            acc[ni][r] = x;
            s[r] += x*cm; q[r] += x*x*cm;
        }
    }
    #pragma unroll
    for (int o = 1; o < 16; o <<= 1)
        #pragma unroll
        for (int r = 0; r < 4; r++) {
            s[r] += __shfl_xor(s[r], o, 64);
            q[r] += __shfl_xor(q[r], o, 64);
        }
    float mu[4], rs[4], mx[4];
    #pragma unroll
    for (int r = 0; r < 4; r++) {
        mu[r] = s[r] * (1.0f/KWW);
        float var = q[r] * (1.0f/KWW) - mu[r]*mu[r];
        rs[r] = rsqrtf(var + 1e-5f);
        mx[r] = -1e30f;
    }
    #pragma unroll
    for (int ni = 0; ni < 14; ni++) {
        int col = ni*16 + mrow;
        bool vc = col < KWW;
        #pragma unroll
        for (int r = 0; r < 4; r++) {
            float x = (acc[ni][r] - mu[r]) * rs[r] * gls[col] + bls[col];
            acc[ni][r] = x;
            if (vc) mx[r] = fmaxf(mx[r], x);
        }
    }
    #pragma unroll
    for (int o = 1; o < 16; o <<= 1)
        #pragma unroll
        for (int r = 0; r < 4; r++)
            mx[r] = fmaxf(mx[r], __shfl_xor(mx[r], o, 64));
    float se[4] = {};
    #pragma unroll
    for (int ni = 0; ni < 14; ni++) {
        int col = ni*16 + mrow;
        float cm = (col < KWW) ? 1.f : 0.f;
        #pragma unroll
        for (int r = 0; r < 4; r++) {
            float p = __expf(acc[ni][r] - mx[r]) * cm;
            acc[ni][r] = p;
            se[r] += p;
        }
    }
    #pragma unroll
    for (int o = 1; o < 16; o <<= 1)
        #pragma unroll
        for (int r = 0; r < 4; r++)
            se[r] += __shfl_xor(se[r], o, 64);
    unsigned short* Pb = PT + (size_t)bh*NP*NP;
    int row0 = bm + wv*16 + quad*4;
    float inv0 = 1.0f/se[0], inv1 = 1.0f/se[1], inv2 = 1.0f/se[2], inv3 = 1.0f/se[3];
    #pragma unroll
    for (int ni = 0; ni < 14; ni++) {
        int col = ni*16 + mrow;
        if (col >= KWW) continue;
        if (row0 + 3 < NN) {
            us4 o = { f2bf(acc[ni][0]*inv0), f2bf(acc[ni][1]*inv1),
                      f2bf(acc[ni][2]*inv2), f2bf(acc[ni][3]*inv3) };
            *(us4*)&Pb[(size_t)col*NP + row0] = o;
        } else {
            float invs[4] = {inv0, inv1, inv2, inv3};
            #pragma unroll
            for (int r = 0; r < 4; r++)
                if (row0 + r < NN)
                    Pb[(size_t)col*NP + row0 + r] = f2bf(acc[ni][r]*invs[r]);
        }
    }
}

// ---------------------------------------------------------------------------
// Fused yv + fc2, split by d: grid (4, BHH). Paired iterations for ILP.
__global__ __launch_bounds__(256) void attn_out2(
    const unsigned short* __restrict__ PT,   // [bh][NP][NP]
    const unsigned short* __restrict__ vT,   // [bh][DD][NP] (n-pad zeroed)
    const unsigned short* __restrict__ fw,   // fc2_wt [NP][NP] (pad rows/cols zero)
    const float* __restrict__ bias,          // fc2_b [197]
    float* __restrict__ x1)
{
    int dt = blockIdx.x;                 // d-tile 0..3
    int bh = blockIdx.y; int b = bh / HH, h = bh - b*HH;
    __shared__ unsigned short yT[16*232];
    int wv = threadIdx.x >> 6, lane = threadIdx.x & 63;
    int quad = lane >> 4, mrow = lane & 15;
    const unsigned short* Pb = PT + (size_t)bh*NP*NP;
    const unsigned short* Vb = vT + (size_t)bh*DD*NP + (size_t)(dt*16)*NP;

    short8 bfv[7];
    #pragma unroll
    for (int kc = 0; kc < 7; kc++)
        bfv[kc] = *(const short8*)&Vb[(size_t)mrow*NP + kc*32 + quad*8];
    // Stage A: 14 kw-tiles over 4 waves, paired for ILP
    #pragma unroll
    for (int i = 0; i < 2; i++) {
        int t0 = wv + i*8, t1 = t0 + 4;
        bool v1 = t1 < 14;
        floatx4 a0 = (floatx4){0.f,0.f,0.f,0.f};
        floatx4 a1 = (floatx4){0.f,0.f,0.f,0.f};
        #pragma unroll
        for (int kc = 0; kc < 7; kc++) {
            short8 p0 = *(const short8*)&Pb[(size_t)(t0*16 + mrow)*NP + kc*32 + quad*8];
            a0 = __builtin_amdgcn_mfma_f32_16x16x32_bf16(p0, bfv[kc], a0, 0, 0, 0);
            if (v1) {
                short8 p1 = *(const short8*)&Pb[(size_t)(t1*16 + mrow)*NP + kc*32 + quad*8];
                a1 = __builtin_amdgcn_mfma_f32_16x16x32_bf16(p1, bfv[kc], a1, 0, 0, 0);
            }
        }
        us4 o0 = { f2bf(a0[0]), f2bf(a0[1]), f2bf(a0[2]), f2bf(a0[3]) };
        *(us4*)&yT[mrow*232 + t0*16 + quad*4] = o0;
        if (v1) {
            us4 o1 = { f2bf(a1[0]), f2bf(a1[1]), f2bf(a1[2]), f2bf(a1[3]) };
            *(us4*)&yT[mrow*232 + t1*16 + quad*4] = o1;
        }
    }
    __syncthreads();

    short8 yf[7];
    #pragma unroll
    for (int kc = 0; kc < 7; kc++)
        yf[kc] = *(const short8*)&yT[mrow*232 + kc*32 + quad*8];
    float* xb = x1 + (size_t)b*NN*CC + (size_t)h*DD + dt*16 + mrow;
    // Stage B: 13 n-tiles over 4 waves, paired for ILP
    #pragma unroll
    for (int i = 0; i < 2; i++) {
        int n0t = wv + i*8, n1t = n0t + 4;
        bool v1 = n1t < 13;
        floatx4 a0 = (floatx4){0.f,0.f,0.f,0.f};
        floatx4 a1 = (floatx4){0.f,0.f,0.f,0.f};
        #pragma unroll
        for (int kc = 0; kc < 7; kc++) {
            short8 f0 = *(const short8*)&fw[(size_t)(n0t*16 + mrow)*NP + kc*32 + quad*8];
            a0 = __builtin_amdgcn_mfma_f32_16x16x32_bf16(f0, yf[kc], a0, 0, 0, 0);
            if (v1) {
                short8 f1 = *(const short8*)&fw[(size_t)(n1t*16 + mrow)*NP + kc*32 + quad*8];
                a1 = __builtin_amdgcn_mfma_f32_16x16x32_bf16(f1, yf[kc], a1, 0, 0, 0);
            }
        }
        #pragma unroll
        for (int r = 0; r < 4; r++) {
            int n = n0t*16 + quad*4 + r;
            if (n < NN) xb[(size_t)n*CC] += a0[r] + bias[n];
        }
        if (v1) {
            #pragma unroll
            for (int r = 0; r < 4; r++) {
                int n = n1t*16 + quad*4 + r;
                if (n < NN) xb[(size_t)n*CC] += a1[r] + bias[n];
            }
        }
    }
}

// ---------------------------------------------------------------------------
__global__ void init_kernel(const float* __restrict__ x, float* __restrict__ x1,
                            float* __restrict__ x2, int n) {
    int i = blockIdx.x*256 + threadIdx.x;
    if (i < n) { float v = x[i]; x1[i] = v; x2[i] = v; }
}
__global__ void final_kernel(const float* __restrict__ x1, const float* __restrict__ x2,
                             float* __restrict__ o, int n) {
    int i = blockIdx.x*256 + threadIdx.x;
    if (i < n) o[i] = 0.5f*(x1[i]+x2[i]);
}

// ---------------------------------------------------------------------------
extern "C" void kernel_launch(void* const* d_in, const int* in_sizes, int n_in,
                              void* d_out, int out_size, void* d_ws, size_t ws_size,
                              hipStream_t stream) {
    const float* x     = (const float*)d_in[0];
    const float* qkv_w = (const float*)d_in[1];
    const float* fc_w  = (const float*)d_in[2];
    const float* fc_b  = (const float*)d_in[3];
    const float* alng  = (const float*)d_in[4];
    const float* alnb  = (const float*)d_in[5];
    const float* fc2w  = (const float*)d_in[6];
    const float* fc2b  = (const float*)d_in[7];
    const float* w1    = (const float*)d_in[8];
    const float* b1    = (const float*)d_in[9];
    const float* w2    = (const float*)d_in[10];
    const float* b2    = (const float*)d_in[11];
    const float* flng  = (const float*)d_in[12];
    const float* flnb  = (const float*)d_in[13];
    const float* glng  = (const float*)d_in[14];
    const float* glnb  = (const float*)d_in[15];
    float* out = (float*)d_out;

    float* ws = (float*)d_ws;
    size_t off = 0;
    float* x1 = ws + off; off += (size_t)RR*CC;
    float* x2 = ws + off; off += (size_t)RR*CC;
    float* part = ws + off; off += (size_t)2*RR*CC;     // MLP2 split-K partials
    unsigned short* lnb = (unsigned short*)(ws + off); off += (size_t)RR*CC/2;
    // qkv bf16 region: q[bh][n][64], k[bh][n][64], vT[bh][64][NP]
    unsigned short* qkvo = (unsigned short*)(ws + off);
    unsigned short* qb = qkvo;
    unsigned short* kb = qkvo + (size_t)BHH*NN*DD;
    unsigned short* vT = qkvo + (size_t)2*BHH*NN*DD;
    off += ((size_t)2*BHH*NN*DD + (size_t)BHH*DD*NP + 1) / 2;
    unsigned short* PT   = (unsigned short*)(ws + off); off += (size_t)BHH*NP*NP/2;
    unsigned short* hid  = (unsigned short*)(ws + off); off += (size_t)RR*HIDD/2;
    unsigned short* qkv_wt = (unsigned short*)(ws + off); off += (size_t)3*CC*CC/2;
    unsigned short* w1t    = (unsigned short*)(ws + off); off += (size_t)CC*HIDD/2;
    unsigned short* w2t    = (unsigned short*)(ws + off); off += (size_t)CC*HIDD/2;
    unsigned short* fc_wt  = (unsigned short*)(ws + off); off += (size_t)NN*NP/2 + 16;
    unsigned short* fc2_wt = (unsigned short*)(ws + off); off += (size_t)NP*NP/2 + 16;

    // Zero pads: vT (n-pad cols must be 0), fc2_wt (pad rows read by attn_out2).
    hipMemsetAsync(vT, 0, (size_t)BHH*DD*NP*2, stream);
    hipMemsetAsync(fc2_wt, 0, (size_t)NP*NP*2, stream);

    // Weight prep: bf16 transposed (+padded) copies, once per launch.
    transpose_cast<<<dim3(72, 24), 256, 0, stream>>>(qkv_w, qkv_wt, CC, 3*CC, CC);
    transpose_cast<<<dim3(96, 24), 256, 0, stream>>>(w1, w1t, CC, HIDD, CC);
    transpose_cast<<<dim3(24, 96), 256, 0, stream>>>(w2, w2t, HIDD, CC, HIDD);
    transpose_cast<<<dim3(7, 7),   256, 0, stream>>>(fc_w,  fc_wt,  NN, KWW, NP);
    transpose_cast<<<dim3(7, 7),   256, 0, stream>>>(fc2w,  fc2_wt, KWW, NN, NP);

    const int nel = RR*CC;
    init_kernel<<<(nel+255)/256, 256, 0, stream>>>(x, x1, x2, nel);

    const int MT = (RR + 127) / 128;   // 50 row-tiles
    // f-LN for layer 0 (subsequent f-LNs are fused into reduce_ln)
    ln768_kernel<<<RR, 256, 0, stream>>>(x2, flng, flnb, lnb);
    for (int l = 0; l < NL; l++) {
        // --- attention branch: y1 = x1 + attn(LN(x2)) ---  (lnb holds f-LN(x2))
        gemm_bf16<128,128,4,4,2,4,1><<<dim3(3*CC/128, MT), 256, 0, stream>>>(
            lnb, qkv_wt, nullptr, nullptr, qb, RR, 3*CC, CC);
        // fused qk + fc + LN + softmax -> PT (transposed bf16)
        attn_score<<<dim3(4, BHH), 256, 0, stream>>>(
            qb, kb, fc_wt, fc_b, alng, alnb, PT);
        // fused yv + fc2 -> x1 += (split by d: 4 blocks/bh)
        attn_out2<<<dim3(4, BHH), 256, 0, stream>>>(PT, vT, fc2_wt, fc2b, x1);
        // --- mlp branch: y2 = x2 + mlp(LN(y1)) ---
        ln768_kernel<<<RR, 256, 0, stream>>>(x1, glng + l*CC, glnb + l*CC, lnb);
        gemm_bf16<128,128,4,4,2,2,1><<<dim3(HIDD/128, MT), 256, 0, stream>>>(
            lnb, w1t, b1, nullptr, hid, RR, HIDD, CC);
        // MLP2: split-K=2, BN=128: 6 x 50 x 2 = 600 blocks
        gemm_bf16<128,128,4,4,2,5,2><<<dim3(CC/128, MT, 2), 256, 0, stream>>>(
            hid, w2t, nullptr, part, nullptr, RR, CC, HIDD);
        // x2 += part0+part1+b2, fused with next layer's f-LN -> lnb
        reduce_ln<<<RR, 256, 0, stream>>>(
            x2, part, b2, flng + ((l+1 < NL) ? (l+1)*CC : 0),
            flnb + ((l+1 < NL) ? (l+1)*CC : 0), lnb, (l+1 < NL) ? 1 : 0);
    }
    final_kernel<<<(nel+255)/256, 256, 0, stream>>>(x1, x2, out, nel);
}